// Round 11
// baseline (861.895 us; speedup 1.0000x reference)
//
#include <hip/hip_runtime.h>
#include <math.h>

#define TWO32F 4294967296.0f

// ---- Bit-exact replica of numpy's SIMD float32 exp (loops_exponent_log) ----
// Cephes-style: RNE quadrant via FMA magic round, 2-step Cody-Waite, all-FMA
// Horner with Cephes coefficients, p*r^2+r, +1, exact 2^q scale.
__device__ __forceinline__ float np_expf(float x) {
    const float LOG2E = 1.44269504088896341f;   // rounds to 0x3FB8AA3B
    const float MAGIC = 12582912.0f;            // 1.5 * 2^23 (RNE int round)
    const float CW1 = 0.693359375f;             // ln2 hi
    const float CW2 = -2.12194440e-4f;          // ln2 lo
    float q = __builtin_fmaf(x, LOG2E, MAGIC);  // single-rounded x*log2e+magic
    q = q - MAGIC;                              // q = RNE(x*log2e), exact int
    float r = __builtin_fmaf(-q, CW1, x);       // fnmadd
    r = __builtin_fmaf(-q, CW2, r);             // fnmadd
    float p = 1.9875691500e-4f;
    p = __builtin_fmaf(p, r, 1.3981999507e-3f);
    p = __builtin_fmaf(p, r, 8.3334519073e-3f);
    p = __builtin_fmaf(p, r, 4.1665795894e-2f);
    p = __builtin_fmaf(p, r, 1.6666665459e-1f);
    p = __builtin_fmaf(p, r, 5.0000001201e-1f);
    float r2 = r * r;                           // 1 rounding
    p = __builtin_fmaf(p, r2, r);               // p*r^2 + r, single-rounded
    p = p + 1.0f;                               // 1 rounding
    return ldexpf(p, (int)q);                   // exact 2^q scale (== scalef)
}

// sigmoid(w) = 1/(1+exp(-w)), one IEEE rounding per source op.
__device__ __forceinline__ float sigmoid_np(float w) {
    #pragma clang fp contract(off)
    float e = np_expf(-w);
    float d = 1.0f + e;          // 1 rounding
    return 1.0f / d;             // IEEE CR divide
}

__device__ __forceinline__ float soft_xor(float x, float y) {
    #pragma clang fp contract(off)
    float wx = 10.0f * (x - 0.5f);   // 2 roundings, no fusion
    float xs = sigmoid_np(wx);
    float wy = 10.0f * (y - 0.5f);
    float ys = sigmoid_np(wy);
    float omys = 1.0f - ys;
    float t1   = xs * omys;
    float omxs = 1.0f - xs;
    float t2   = omxs * ys;
    float s    = t1 + t2;
    float t12  = t1 * t2;
    float r    = s - t12;
    r = fmaxf(r, 0.0f);
    r = fminf(r, 1.0f);
    return r;
}

__device__ __forceinline__ float soft_add(float x, float y) {
    #pragma clang fp contract(off)
    float s  = x + y;
    float d  = s - 1.0f;
    float w  = 10.0f * d;
    float sg = sigmoid_np(w);
    return s - sg;
}

// rotate_left in the fraction-of-2^32 domain; every step exact in f32 except
// the single sl+sr add, which has the same 1 rounding as the reference.
template <int N>
__device__ __forceinline__ float rotl(float x) {
    #pragma clang fp contract(off)
    const float PN = (float)(1u << N);      // 2^N exact
    const float PN_INV32 = PN / TWO32F;     // 2^(N-32) exact
    float xs = x * TWO32F;                  // exact
    float a  = xs * PN;                     // exact
    float q1 = floorf(a * (1.0f / TWO32F));
    float sl = a - q1 * TWO32F;             // exact mod 2^32
    float sr = xs * PN_INV32;               // exact
    float s2 = sl + sr;                     // 1 rounding
    float q2 = floorf(s2 * (1.0f / TWO32F));
    float r  = s2 - q2 * TWO32F;            // exact mod 2^32
    return r * (1.0f / TWO32F);             // exact
}

__device__ __forceinline__ void qround(float& y0, float& y1, float& y2, float& y3) {
    y1 = soft_xor(y1, rotl<7>(soft_add(y0, y3)));
    y2 = soft_xor(y2, rotl<9>(soft_add(y1, y0)));
    y3 = soft_xor(y3, rotl<13>(soft_add(y2, y1)));
    y0 = soft_xor(y0, rotl<18>(soft_add(y3, y2)));
}

__global__ __launch_bounds__(256) void salsa20_soft_kernel(
    const float* __restrict__ pt, const float* __restrict__ key,
    const float* __restrict__ nonce, float* __restrict__ out, int B) {
    #pragma clang fp contract(off)
    int i = blockIdx.x * 256 + threadIdx.x;
    if (i >= B) return;

    const float C0 = 1634760805.0f / 4294967296.0f;
    const float C1 = 857760878.0f  / 4294967296.0f;
    const float C2 = 2036477234.0f / 4294967296.0f;
    const float C3 = 1797285236.0f / 4294967296.0f;

    const float4* k4 = reinterpret_cast<const float4*>(key + (size_t)i * 8);
    float4 ka = k4[0];
    float4 kb = k4[1];
    float2 nn = reinterpret_cast<const float2*>(nonce)[i];

    float w[16];
    w[0]  = C0;   w[1]  = ka.x; w[2]  = ka.y; w[3]  = ka.z;
    w[4]  = ka.w; w[5]  = C1;   w[6]  = nn.x; w[7]  = nn.y;
    w[8]  = 0.0f; w[9]  = 0.0f; w[10] = C2;   w[11] = kb.x;
    w[12] = kb.y; w[13] = kb.z; w[14] = kb.w; w[15] = C3;

    float init[16];
    #pragma unroll
    for (int j = 0; j < 16; ++j) init[j] = w[j];

    #pragma unroll 1
    for (int r = 0; r < 10; ++r) {
        // column rounds
        qround(w[0],  w[4],  w[8],  w[12]);
        qround(w[5],  w[9],  w[13], w[1]);
        qround(w[10], w[14], w[2],  w[6]);
        qround(w[15], w[3],  w[7],  w[11]);
        // row rounds
        qround(w[0],  w[1],  w[2],  w[3]);
        qround(w[5],  w[6],  w[7],  w[4]);
        qround(w[10], w[11], w[8],  w[9]);
        qround(w[15], w[12], w[13], w[14]);
    }

    const float4* p4 = reinterpret_cast<const float4*>(pt + (size_t)i * 16);
    float4* o4 = reinterpret_cast<float4*>(out + (size_t)i * 16);
    #pragma unroll
    for (int q = 0; q < 4; ++q) {
        float4 p = p4[q];
        float4 o;
        o.x = soft_xor(p.x, soft_add(w[4 * q + 0], init[4 * q + 0]));
        o.y = soft_xor(p.y, soft_add(w[4 * q + 1], init[4 * q + 1]));
        o.z = soft_xor(p.z, soft_add(w[4 * q + 2], init[4 * q + 2]));
        o.w = soft_xor(p.w, soft_add(w[4 * q + 3], init[4 * q + 3]));
        o4[q] = o;
    }
}

extern "C" void kernel_launch(void* const* d_in, const int* in_sizes, int n_in,
                              void* d_out, int out_size, void* d_ws, size_t ws_size,
                              hipStream_t stream) {
    const float* pt    = (const float*)d_in[0];
    const float* key   = (const float*)d_in[1];
    const float* nonce = (const float*)d_in[2];
    float* out = (float*)d_out;
    int B = in_sizes[0] / 16;
    int grid = (B + 255) / 256;
    salsa20_soft_kernel<<<grid, 256, 0, stream>>>(pt, key, nonce, out, B);
}